// Round 7
// baseline (739.684 us; speedup 1.0000x reference)
//
#include <hip/hip_runtime.h>
#include <hip/hip_cooperative_groups.h>

namespace cg = cooperative_groups;

#define TOK 2048
#define DDIM 1024
#define HDIM 1408
#define ENUM 8
#define NSLOT (2 * TOK)
#define UP_NB 22   // HDIM / 64
#define UP_KS 32   // DDIM / 32
#define DN_NB 16   // DDIM / 64
#define DN_KS 44   // HDIM / 32
#define DN_KH 22   // DN_KS / 2 (K-split halves)
#define TC_W1_BLK 2816   // 16 z * 22 nb * 8 ksg
#define CAST_ITEMS 4224  // + 8 e * 16 nb * 11 ksg
#define GATE_ITEMS 512   // 2048 tokens / 4
#define PH1_ITEMS (CAST_ITEMS + GATE_ITEMS)
#define UP_TILES 2816    // e(8) * my(16) * nb(22)
#define DN_TILES 2048    // z(16) * my(16) * nb(8)

typedef unsigned int uint;
typedef unsigned short ushort;
typedef unsigned long long ull;

using bf16x8 = __attribute__((ext_vector_type(8))) __bf16;
using f32x4  = __attribute__((ext_vector_type(4))) float;

// shared-memory union: up and down layouts are both exactly 33280 B
union SMem {
    struct {
        ushort As[2][128][32];
        ushort Bgs[2][64][32];
        ushort Bus[2][64][32];
        int rowslot[128];
    } u;
    struct {
        ushort As[2][128][32];
        ushort Bs[2][128][32];
        int rowslot[128];
    } d;
};

__device__ __forceinline__ float silu_f(float g) {
    return g / (1.0f + __expf(-g));
}

__device__ __forceinline__ ushort cvt_bf16(float f) {
    uint u = __float_as_uint(f);
    u += 0x7FFFu + ((u >> 16) & 1u);   // RNE
    return (ushort)(u >> 16);
}

// async global->LDS: per-lane global address, LDS dest = wave-uniform base + lane*16
__device__ __forceinline__ void gl2lds16(const void* g, void* l) {
    __builtin_amdgcn_global_load_lds(
        (const __attribute__((address_space(1))) uint*)g,
        (__attribute__((address_space(3))) uint*)l, 16, 0, 0);
}

// ---- phase 1a: weight precast, LDS-free strided-read transpose -----------
__device__ __forceinline__ void cast_item(
    int item, int tid, const float* w1g, const float* w1u, const float* w2,
    ushort* BgP, ushort* BuP, ushort* W2P)
{
    const float* src; ushort* dst; int N, KS, NB, e, nb, ks0;
    if (item < TC_W1_BLK) {
        const int z = item / 176;           // 176 = 22 nb * 8 ksg
        const int rem = item - z * 176;
        src = (z & 8) ? w1u : w1g;
        dst = (z & 8) ? BuP : BgP;
        N = HDIM; KS = UP_KS; NB = UP_NB; e = z & 7;
        nb = rem >> 3; ks0 = (rem & 7) * 4;
    } else {
        const int b2 = item - TC_W1_BLK;
        e = b2 / 176;                       // 176 = 16 nb * 11 ksg
        const int rem = b2 - e * 176;
        src = w2; dst = W2P;
        N = DDIM; KS = DN_KS; NB = DN_NB;
        nb = rem / 11; ks0 = (rem - nb * 11) * 4;
    }
    const int kg = tid & 3;
    const int nn = tid >> 2;
    const float* sb = src + (size_t)e * ((size_t)KS * 32) * N + nb * 64 + nn;
    ushort* db = dst + ((((size_t)e * NB + nb) * KS) + ks0) * 2048 + nn * 32 + kg * 8;
#pragma unroll
    for (int ksi = 0; ksi < 4; ++ksi) {
        const float* st = sb + (size_t)((ks0 + ksi) * 32 + kg * 8) * N;
        float v[8];
#pragma unroll
        for (int j = 0; j < 8; ++j) v[j] = st[(size_t)j * N];
        ushort o[8];
#pragma unroll
        for (int j = 0; j < 8; ++j) o[j] = cvt_bf16(v[j]);
        *(uint4*)(db + ksi * 2048) = *(uint4*)o;
    }
}

// ---- phase 1b: gate1, 4 tokens/item, one wave each ------------------------
__device__ __forceinline__ void gate_item(
    int item, int tid, const float* x, const float* gw,
    int* tinfo, float* wslot, ushort* xb)
{
    const int t = item * 4 + (tid >> 6);
    const int lane = tid & 63;
    const float* xr = x + (size_t)t * DDIM;
    ushort* xbr = xb + (size_t)t * DDIM;
    float xv[16];
#pragma unroll
    for (int i = 0; i < 16; ++i) xv[i] = xr[lane + 64 * i];
#pragma unroll
    for (int i = 0; i < 16; ++i) xbr[lane + 64 * i] = cvt_bf16(xv[i]);
    float logit[ENUM];
#pragma unroll
    for (int e = 0; e < ENUM; ++e) {
        const float* gr = gw + (size_t)e * DDIM;
        float acc = 0.f;
#pragma unroll
        for (int i = 0; i < 16; ++i) acc += xv[i] * gr[lane + 64 * i];
#pragma unroll
        for (int s = 32; s > 0; s >>= 1) acc += __shfl_xor(acc, s, 64);
        logit[e] = acc;
    }
    if (lane == 0) {
        float mx = logit[0];
#pragma unroll
        for (int e = 1; e < ENUM; ++e) mx = fmaxf(mx, logit[e]);
        float p[ENUM]; float se = 0.f;
#pragma unroll
        for (int e = 0; e < ENUM; ++e) { p[e] = __expf(logit[e] - mx); se += p[e]; }
        float inv = 1.0f / se;
#pragma unroll
        for (int e = 0; e < ENUM; ++e) p[e] *= inv;
        int i0 = 0;
#pragma unroll
        for (int e = 1; e < ENUM; ++e) if (p[e] > p[i0]) i0 = e;
        int i1 = (i0 == 0) ? 1 : 0;
#pragma unroll
        for (int e = 0; e < ENUM; ++e) if (e != i0 && p[e] > p[i1]) i1 = e;
        tinfo[t] = i0 | (i1 << 4);
        wslot[(t << 1)] = p[i0];
        wslot[(t << 1) | 1] = p[i1];
    }
}

__device__ __forceinline__ void phase1(
    int bid, int gdim, int tid,
    const float* w1g, const float* w1u, const float* w2,
    ushort* BgP, ushort* BuP, ushort* W2P,
    const float* x, const float* gw,
    int* tinfo, float* wslot, ushort* xb)
{
    for (int item = bid; item < PH1_ITEMS; item += gdim) {
        if (item < CAST_ITEMS) cast_item(item, tid, w1g, w1u, w2, BgP, BuP, W2P);
        else gate_item(item - CAST_ITEMS, tid, x, gw, tinfo, wslot, xb);
    }
}

// ---- phase 2: gate2 expert compaction, wave-aggregated ballot -------------
__device__ __forceinline__ void phase2(
    int bid, int gdim, int tid,
    const int* tinfo, int* counts, int* toks)
{
    __shared__ int s_cnt;
    const int lane = tid & 63;
    for (int e = bid; e < ENUM; e += gdim) {
        if (tid == 0) s_cnt = 0;
        __syncthreads();
        int* te = toks + e * TOK;
        for (int t = tid; t < TOK; t += 256) {
            int info = tinfo[t];
            ull m0 = __ballot((info & 15) == e);
            if (m0) {
                int base;
                if (lane == 0) base = atomicAdd(&s_cnt, __popcll(m0));
                base = __shfl(base, 0, 64);
                if ((m0 >> lane) & 1)
                    te[base + __popcll(m0 & ((1ull << lane) - 1))] = (t << 1);
            }
            ull m1 = __ballot((info >> 4) == e);
            if (m1) {
                int base;
                if (lane == 0) base = atomicAdd(&s_cnt, __popcll(m1));
                base = __shfl(base, 0, 64);
                if ((m1 >> lane) & 1)
                    te[base + __popcll(m1 & ((1ull << lane) - 1))] = (t << 1) | 1;
            }
        }
        __syncthreads();
        if (tid == 0) counts[e] = s_cnt;
        __syncthreads();
    }
}

// ---- phase 3: up tile: Hbuf[slot] = silu(x@w1g)*(x@w1u); TM=128 TN=64 ----
__device__ __forceinline__ void up_tile(
    SMem* sm, int vt, int tid,
    const ushort* xb, const ushort* BgP, const ushort* BuP,
    const int* counts, const int* toks, ushort* Hbuf)
{
    const int e = vt / 352;              // 352 = 16 my * 22 nb
    const int rem = vt - e * 352;
    const int my = rem / 22;
    const int nb = rem - my * 22;
    const int cnt = counts[e];
    const int m0 = my * 128;
    if (m0 >= cnt) return;
    const int w = tid >> 6;
    const int lane = tid & 63;
    const int q = lane >> 4;
    const int l15 = lane & 15;
    const int wr = w >> 1;   // m half (64 rows)
    const int wc = w & 1;    // n half (32 cols)

    __syncthreads();   // LDS reuse across grid-stride iterations
    if (tid < 128) sm->u.rowslot[tid] = (m0 + tid < cnt) ? toks[e * TOK + m0 + tid] : -1;
    __syncthreads();

    // staging: XOR-swizzle via pre-swizzled global chunk (clog)
    const int srow = w * 16 + (lane >> 2);
    const int clog = (((lane & 3) + 4 - ((srow >> 1) & 3)) & 3) * 8;
    const int as0 = sm->u.rowslot[srow];
    const int as1 = sm->u.rowslot[srow + 64];
    const ushort* agp0 = xb + (size_t)(as0 < 0 ? 0 : (as0 >> 1)) * DDIM + clog;
    const ushort* agp1 = xb + (size_t)(as1 < 0 ? 0 : (as1 >> 1)) * DDIM + clog;
    const size_t tb = (size_t)(e * UP_NB + nb) * UP_KS * 2048;
    const ushort* bgp = BgP + tb + srow * 32 + clog;
    const ushort* bup = BuP + tb + srow * 32 + clog;

    const int coff = ((q + (l15 >> 1)) & 3) * 8;

    f32x4 accg[4][2], accu[4][2];
#pragma unroll
    for (int i = 0; i < 4; ++i)
#pragma unroll
        for (int j = 0; j < 2; ++j) { accg[i][j] = (f32x4)0.f; accu[i][j] = (f32x4)0.f; }

#define UP_PREFETCH(KSV, B)                                              \
    {                                                                    \
        gl2lds16(agp0 + (KSV) * 32, &sm->u.As[B][w * 16][0]);            \
        gl2lds16(agp1 + (KSV) * 32, &sm->u.As[B][64 + w * 16][0]);       \
        gl2lds16(bgp + (size_t)(KSV) * 2048, &sm->u.Bgs[B][w * 16][0]);  \
        gl2lds16(bup + (size_t)(KSV) * 2048, &sm->u.Bus[B][w * 16][0]);  \
    }

    UP_PREFETCH(0, 0);
    __syncthreads();

    for (int ks = 0; ks < UP_KS; ++ks) {
        const int cur = ks & 1;
        const int nxt = cur ^ 1;
        if (ks + 1 < UP_KS) UP_PREFETCH(ks + 1, nxt);

        bf16x8 a[4], bg[2], bu[2];
#pragma unroll
        for (int mi = 0; mi < 4; ++mi)
            a[mi] = *(const bf16x8*)&sm->u.As[cur][wr * 64 + mi * 16 + l15][coff];
#pragma unroll
        for (int ni = 0; ni < 2; ++ni) {
            bg[ni] = *(const bf16x8*)&sm->u.Bgs[cur][wc * 32 + ni * 16 + l15][coff];
            bu[ni] = *(const bf16x8*)&sm->u.Bus[cur][wc * 32 + ni * 16 + l15][coff];
        }
#pragma unroll
        for (int mi = 0; mi < 4; ++mi)
#pragma unroll
            for (int ni = 0; ni < 2; ++ni) {
                accg[mi][ni] = __builtin_amdgcn_mfma_f32_16x16x32_bf16(a[mi], bg[ni], accg[mi][ni], 0, 0, 0);
                accu[mi][ni] = __builtin_amdgcn_mfma_f32_16x16x32_bf16(a[mi], bu[ni], accu[mi][ni], 0, 0, 0);
            }
        __syncthreads();   // drains prefetch vmem + protects buffer swap
    }
#undef UP_PREFETCH

#pragma unroll
    for (int mi = 0; mi < 4; ++mi) {
#pragma unroll
        for (int r = 0; r < 4; ++r) {
            int ml = wr * 64 + mi * 16 + q * 4 + r;
            int slot = sm->u.rowslot[ml];
            if (slot < 0) continue;
            ushort* hrow = Hbuf + (size_t)slot * HDIM + nb * 64 + wc * 32 + l15;
#pragma unroll
            for (int ni = 0; ni < 2; ++ni)
                hrow[ni * 16] = cvt_bf16(silu_f(accg[mi][ni][r]) * accu[mi][ni][r]);
        }
    }
}

// ---- phase 4: down tile: Ybuf partials; TM=128 TN=128, K-split 2 ---------
__device__ __forceinline__ void down_tile(
    SMem* sm, int vt, int tid,
    const ushort* Hbuf, const ushort* W2P,
    const int* counts, const int* toks, float* Ybuf)
{
    const int z = vt / 128;              // 128 = 16 my * 8 nb
    const int rem = vt - z * 128;
    const int my = rem >> 3;
    const int nb = rem & 7;
    const int e = z >> 1;
    const int kh = z & 1;
    const int cnt = counts[e];
    const int m0 = my * 128;
    if (m0 >= cnt) return;
    const int w = tid >> 6;
    const int lane = tid & 63;
    const int q = lane >> 4;
    const int l15 = lane & 15;
    const int wr = w >> 1;
    const int wc = w & 1;

    __syncthreads();
    if (tid < 128) sm->d.rowslot[tid] = (m0 + tid < cnt) ? toks[e * TOK + m0 + tid] : -1;
    __syncthreads();

    const int srow = w * 16 + (lane >> 2);
    const int clog = (((lane & 3) + 4 - ((srow >> 1) & 3)) & 3) * 8;
    const int as0 = sm->d.rowslot[srow];
    const int as1 = sm->d.rowslot[srow + 64];
    const ushort* agp0 = Hbuf + (size_t)(as0 < 0 ? 0 : as0) * HDIM + kh * (DN_KH * 32) + clog;
    const ushort* agp1 = Hbuf + (size_t)(as1 < 0 ? 0 : as1) * HDIM + kh * (DN_KH * 32) + clog;
    const int nb2 = nb * 2;
    const ushort* bp0 = W2P + ((size_t)(e * DN_NB + nb2) * DN_KS + kh * DN_KH) * 2048 + srow * 32 + clog;
    const ushort* bp1 = W2P + ((size_t)(e * DN_NB + nb2 + 1) * DN_KS + kh * DN_KH) * 2048 + srow * 32 + clog;

    const int coff = ((q + (l15 >> 1)) & 3) * 8;

    f32x4 acc[4][4];
#pragma unroll
    for (int i = 0; i < 4; ++i)
#pragma unroll
        for (int j = 0; j < 4; ++j) acc[i][j] = (f32x4)0.f;

#define DN_PREFETCH(KSV, B)                                                 \
    {                                                                       \
        gl2lds16(agp0 + (KSV) * 32, &sm->d.As[B][w * 16][0]);               \
        gl2lds16(agp1 + (KSV) * 32, &sm->d.As[B][64 + w * 16][0]);          \
        gl2lds16(bp0 + (size_t)(KSV) * 2048, &sm->d.Bs[B][w * 16][0]);      \
        gl2lds16(bp1 + (size_t)(KSV) * 2048, &sm->d.Bs[B][64 + w * 16][0]); \
    }

    DN_PREFETCH(0, 0);
    __syncthreads();

    for (int ks = 0; ks < DN_KH; ++ks) {
        const int cur = ks & 1;
        const int nxt = cur ^ 1;
        if (ks + 1 < DN_KH) DN_PREFETCH(ks + 1, nxt);

        bf16x8 a[4], b[4];
#pragma unroll
        for (int mi = 0; mi < 4; ++mi)
            a[mi] = *(const bf16x8*)&sm->d.As[cur][wr * 64 + mi * 16 + l15][coff];
#pragma unroll
        for (int ni = 0; ni < 4; ++ni)
            b[ni] = *(const bf16x8*)&sm->d.Bs[cur][wc * 64 + ni * 16 + l15][coff];
#pragma unroll
        for (int mi = 0; mi < 4; ++mi)
#pragma unroll
            for (int ni = 0; ni < 4; ++ni)
                acc[mi][ni] = __builtin_amdgcn_mfma_f32_16x16x32_bf16(a[mi], b[ni], acc[mi][ni], 0, 0, 0);
        __syncthreads();
    }
#undef DN_PREFETCH

    float* Yp = Ybuf + (size_t)kh * NSLOT * DDIM;
#pragma unroll
    for (int mi = 0; mi < 4; ++mi) {
#pragma unroll
        for (int r = 0; r < 4; ++r) {
            int ml = wr * 64 + mi * 16 + q * 4 + r;
            int slot = sm->d.rowslot[ml];
            if (slot < 0) continue;
            float* yr = Yp + (size_t)slot * DDIM + nb * 128 + wc * 64 + l15;
#pragma unroll
            for (int ni = 0; ni < 4; ++ni)
                yr[ni * 16] = acc[mi][ni][r];
        }
    }
}

// ---- phase 5: combine -----------------------------------------------------
__device__ __forceinline__ void phase5(
    int bid, int gdim, int tid,
    const float* Ybuf, const float* wslot, float* y)
{
    const int j = tid * 4;
    for (int t = bid; t < TOK; t += gdim) {
        const float w0 = wslot[2 * t];
        const float w1 = wslot[2 * t + 1];
        const float* y00 = Ybuf + ((size_t)2 * t) * DDIM + j;
        const float* y01 = Ybuf + ((size_t)2 * t + 1) * DDIM + j;
        const float* y10 = y00 + (size_t)NSLOT * DDIM;
        const float* y11 = y01 + (size_t)NSLOT * DDIM;
        float4 a0 = *(const float4*)y00;
        float4 b0 = *(const float4*)y01;
        float4 a1 = *(const float4*)y10;
        float4 b1 = *(const float4*)y11;
        float4 o;
        o.x = w0 * (a0.x + a1.x) + w1 * (b0.x + b1.x);
        o.y = w0 * (a0.y + a1.y) + w1 * (b0.y + b1.y);
        o.z = w0 * (a0.z + a1.z) + w1 * (b0.z + b1.z);
        o.w = w0 * (a0.w + a1.w) + w1 * (b0.w + b1.w);
        *(float4*)(y + (size_t)t * DDIM + j) = o;
    }
}

// ---- cooperative mega-kernel: all phases, grid.sync between --------------
__global__ __launch_bounds__(256, 4) void moe_coop(
    const float* w1g, const float* w1u, const float* w2,
    const float* x, const float* gw,
    ushort* BgP, ushort* BuP, ushort* W2P,
    int* tinfo, float* wslot, ushort* xb,
    int* counts, int* toks, ushort* Hbuf, float* Ybuf, float* y)
{
    __shared__ SMem sm;
    const int tid = threadIdx.x;
    const int bid = blockIdx.x;
    const int gdim = gridDim.x;
    cg::grid_group grid = cg::this_grid();

    phase1(bid, gdim, tid, w1g, w1u, w2, BgP, BuP, W2P, x, gw, tinfo, wslot, xb);
    grid.sync();
    phase2(bid, gdim, tid, tinfo, counts, toks);
    grid.sync();
    for (int vt = bid; vt < UP_TILES; vt += gdim)
        up_tile(&sm, vt, tid, xb, BgP, BuP, counts, toks, Hbuf);
    grid.sync();
    for (int vt = bid; vt < DN_TILES; vt += gdim)
        down_tile(&sm, vt, tid, Hbuf, W2P, counts, toks, Ybuf);
    grid.sync();
    phase5(bid, gdim, tid, Ybuf, wslot, y);
}

// ---- fallback kernels (same phase bodies, separate launches) -------------
__global__ __launch_bounds__(256) void k_ph1(
    const float* w1g, const float* w1u, const float* w2,
    ushort* BgP, ushort* BuP, ushort* W2P,
    const float* x, const float* gw, int* tinfo, float* wslot, ushort* xb)
{
    phase1(blockIdx.x, gridDim.x, threadIdx.x, w1g, w1u, w2, BgP, BuP, W2P, x, gw, tinfo, wslot, xb);
}

__global__ __launch_bounds__(256) void k_ph2(
    const int* tinfo, int* counts, int* toks)
{
    phase2(blockIdx.x, gridDim.x, threadIdx.x, tinfo, counts, toks);
}

__global__ __launch_bounds__(256, 4) void k_up(
    const ushort* xb, const ushort* BgP, const ushort* BuP,
    const int* counts, const int* toks, ushort* Hbuf)
{
    __shared__ SMem sm;
    for (int vt = blockIdx.x; vt < UP_TILES; vt += gridDim.x)
        up_tile(&sm, vt, threadIdx.x, xb, BgP, BuP, counts, toks, Hbuf);
}

__global__ __launch_bounds__(256, 4) void k_dn(
    const ushort* Hbuf, const ushort* W2P,
    const int* counts, const int* toks, float* Ybuf)
{
    __shared__ SMem sm;
    for (int vt = blockIdx.x; vt < DN_TILES; vt += gridDim.x)
        down_tile(&sm, vt, threadIdx.x, Hbuf, W2P, counts, toks, Ybuf);
}

__global__ __launch_bounds__(256) void k_cb(
    const float* Ybuf, const float* wslot, float* y)
{
    phase5(blockIdx.x, gridDim.x, threadIdx.x, Ybuf, wslot, y);
}

extern "C" void kernel_launch(void* const* d_in, const int* in_sizes, int n_in,
                              void* d_out, int out_size, void* d_ws, size_t ws_size,
                              hipStream_t stream) {
    const float* x   = (const float*)d_in[0];
    const float* gw  = (const float*)d_in[1];
    const float* w1g = (const float*)d_in[2];
    const float* w1u = (const float*)d_in[3];
    const float* w2  = (const float*)d_in[4];
    float* y = (float*)d_out;
    char* ws = (char*)d_ws;

    // workspace layout (Ybuf [2 K-halves] aliases BgP/BuP region — dead after up)
    size_t off = 0;
    int*    counts = (int*)(ws + off);   off += 256;
    int*    toks   = (int*)(ws + off);   off += (size_t)ENUM * TOK * 4;   // 64 KB
    float*  wslot  = (float*)(ws + off); off += (size_t)NSLOT * 4;        // 16 KB
    int*    tinfo  = (int*)(ws + off);   off += (size_t)TOK * 4;          // 8 KB
    off = (off + 255) & ~(size_t)255;
    ushort* xb     = (ushort*)(ws + off); off += (size_t)TOK * DDIM * 2;  // 4 MB
    size_t regA = off;                                                    // 46 MB region
    ushort* BgP  = (ushort*)(ws + regA);
    ushort* BuP  = (ushort*)(ws + regA + (size_t)ENUM * DDIM * HDIM * 2);
    float*  Ybuf = (float*)(ws + regA);                                   // 33.6 MB alias
    off = regA + (size_t)2 * ENUM * DDIM * HDIM * 2;
    ushort* W2P  = (ushort*)(ws + off);  off += (size_t)ENUM * HDIM * DDIM * 2; // 23 MB
    ushort* Hbuf = (ushort*)(ws + off);                                         // 11.5 MB

    // try cooperative single-kernel launch; grid = co-resident capacity
    int occ = 0;
    hipError_t qe = hipOccupancyMaxActiveBlocksPerMultiprocessor(
        &occ, (const void*)moe_coop, 256, 0);
    bool done = false;
    if (qe == hipSuccess && occ > 0) {
        int grid = occ * 256;                // 256 CUs on MI355X
        if (grid > UP_TILES) grid = UP_TILES;
        void* args[] = {
            (void*)&w1g, (void*)&w1u, (void*)&w2, (void*)&x, (void*)&gw,
            (void*)&BgP, (void*)&BuP, (void*)&W2P,
            (void*)&tinfo, (void*)&wslot, (void*)&xb,
            (void*)&counts, (void*)&toks, (void*)&Hbuf, (void*)&Ybuf, (void*)&y
        };
        if (hipLaunchCooperativeKernel((const void*)moe_coop, dim3(grid), dim3(256),
                                       args, 0, stream) == hipSuccess)
            done = true;
    }

    if (!done) {
        // fallback: 5 regular launches (round-5-equivalent performance)
        k_ph1<<<PH1_ITEMS, 256, 0, stream>>>(w1g, w1u, w2, BgP, BuP, W2P, x, gw, tinfo, wslot, xb);
        k_ph2<<<ENUM, 256, 0, stream>>>(tinfo, counts, toks);
        k_up<<<UP_TILES, 256, 0, stream>>>(xb, BgP, BuP, counts, toks, Hbuf);
        k_dn<<<DN_TILES, 256, 0, stream>>>(Hbuf, W2P, counts, toks, Ybuf);
        k_cb<<<TOK, 256, 0, stream>>>(Ybuf, wslot, y);
    }
}

// Round 8
// 309.544 us; speedup vs baseline: 2.3896x; 2.3896x over previous
//
#include <hip/hip_runtime.h>

#define TOK 2048
#define DDIM 1024
#define HDIM 1408
#define ENUM 8
#define NSLOT (2 * TOK)
#define UP_NB 22   // HDIM / 64
#define UP_KS 32   // DDIM / 32
#define DN_NB 16   // DDIM / 64
#define DN_KS 44   // HDIM / 32
#define DN_KH 22   // DN_KS / 2 (K-split halves)
#define TC_W1_BLK 2816   // 16 z * 22 nb * 8 ksg
#define CAST_ITEMS 4224  // + 8 e * 16 nb * 11 ksg (w2)
#define GATE_BLKS 32     // 2048 tokens / 64 per block

typedef unsigned int uint;
typedef unsigned short ushort;
typedef unsigned long long ull;

using bf16x8 = __attribute__((ext_vector_type(8))) __bf16;
using f32x4  = __attribute__((ext_vector_type(4))) float;

__device__ __forceinline__ float silu_f(float g) {
    return g / (1.0f + __expf(-g));
}

__device__ __forceinline__ ushort cvt_bf16(float f) {
    uint u = __float_as_uint(f);
    u += 0x7FFFu + ((u >> 16) & 1u);   // RNE
    return (ushort)(u >> 16);
}

// async global->LDS: per-lane global address, LDS dest = wave-uniform base + lane*16
__device__ __forceinline__ void gl2lds16(const void* g, void* l) {
    __builtin_amdgcn_global_load_lds(
        (const __attribute__((address_space(1))) uint*)g,
        (__attribute__((address_space(3))) uint*)l, 16, 0, 0);
}

// ---- kernel 1: weight precast (LDS-free strided transpose, round-5 body)
//      + gate (64 tokens/block: logits, top-2, LDS binning, 8 global
//        atomics/block to reserve toks ranges — replaces gate2 launch) -----
__global__ __launch_bounds__(256) void tcast_gate_kernel(
    const float* __restrict__ w1g, const float* __restrict__ w1u,
    const float* __restrict__ w2, ushort* __restrict__ BgP,
    ushort* __restrict__ BuP, ushort* __restrict__ W2P,
    const float* __restrict__ x, const float* __restrict__ gw,
    int* __restrict__ counts, int* __restrict__ toks,
    float* __restrict__ wslot, ushort* __restrict__ xb)
{
    const int bid = blockIdx.x;
    const int tid = threadIdx.x;

    if (bid < CAST_ITEMS) {
        // ---- weight cast: 4 ks-tiles per block, no LDS (round-5 body) ----
        const float* src; ushort* dst; int N, KS, NB, e, nb, ks0;
        if (bid < TC_W1_BLK) {
            const int z = bid / 176;            // 176 = 22 nb * 8 ksg
            const int rem = bid - z * 176;
            src = (z & 8) ? w1u : w1g;
            dst = (z & 8) ? BuP : BgP;
            N = HDIM; KS = UP_KS; NB = UP_NB; e = z & 7;
            nb = rem >> 3; ks0 = (rem & 7) * 4;
        } else {
            const int b2 = bid - TC_W1_BLK;
            e = b2 / 176;                       // 176 = 16 nb * 11 ksg
            const int rem = b2 - e * 176;
            src = w2; dst = W2P;
            N = DDIM; KS = DN_KS; NB = DN_NB;
            nb = rem / 11; ks0 = (rem - nb * 11) * 4;
        }
        const int kg = tid & 3;
        const int nn = tid >> 2;
        const float* sb = src + (size_t)e * ((size_t)KS * 32) * N + nb * 64 + nn;
        ushort* db = dst + ((((size_t)e * NB + nb) * KS) + ks0) * 2048 + nn * 32 + kg * 8;
#pragma unroll
        for (int ksi = 0; ksi < 4; ++ksi) {
            const float* st = sb + (size_t)((ks0 + ksi) * 32 + kg * 8) * N;
            float v[8];
#pragma unroll
            for (int j = 0; j < 8; ++j) v[j] = st[(size_t)j * N];
            ushort o[8];
#pragma unroll
            for (int j = 0; j < 8; ++j) o[j] = cvt_bf16(v[j]);
            *(uint4*)(db + ksi * 2048) = *(uint4*)o;
        }
        return;
    }

    // ---- gate: 64 tokens per block (4 waves x 16 tokens) ----
    __shared__ int e0l[64], e1l[64];
    __shared__ int hist[ENUM], cursor[ENUM];
    const int base = (bid - CAST_ITEMS) * 64;
    const int w = tid >> 6;
    const int lane = tid & 63;
    if (tid < ENUM) hist[tid] = 0;

    for (int it = 0; it < 16; ++it) {
        const int lt = w * 16 + it;
        const int t = base + lt;
        const float* xr = x + (size_t)t * DDIM;
        ushort* xbr = xb + (size_t)t * DDIM;
        float xv[16];
#pragma unroll
        for (int i = 0; i < 16; ++i) xv[i] = xr[lane + 64 * i];
#pragma unroll
        for (int i = 0; i < 16; ++i) xbr[lane + 64 * i] = cvt_bf16(xv[i]);
        float logit[ENUM];
#pragma unroll
        for (int e = 0; e < ENUM; ++e) {
            const float* gr = gw + (size_t)e * DDIM;
            float acc = 0.f;
#pragma unroll
            for (int i = 0; i < 16; ++i) acc += xv[i] * gr[lane + 64 * i];
#pragma unroll
            for (int s = 32; s > 0; s >>= 1) acc += __shfl_xor(acc, s, 64);
            logit[e] = acc;
        }
        if (lane == 0) {
            float mx = logit[0];
#pragma unroll
            for (int e = 1; e < ENUM; ++e) mx = fmaxf(mx, logit[e]);
            float p[ENUM]; float se = 0.f;
#pragma unroll
            for (int e = 0; e < ENUM; ++e) { p[e] = __expf(logit[e] - mx); se += p[e]; }
            float inv = 1.0f / se;
#pragma unroll
            for (int e = 0; e < ENUM; ++e) p[e] *= inv;
            int i0 = 0;
#pragma unroll
            for (int e = 1; e < ENUM; ++e) if (p[e] > p[i0]) i0 = e;
            int i1 = (i0 == 0) ? 1 : 0;
#pragma unroll
            for (int e = 0; e < ENUM; ++e) if (e != i0 && p[e] > p[i1]) i1 = e;
            wslot[(t << 1)] = p[i0];
            wslot[(t << 1) | 1] = p[i1];
            e0l[lt] = i0;
            e1l[lt] = i1;
        }
    }
    __syncthreads();
    // local histogram (128 LDS atomics on 8 counters — cheap)
    if (tid < 64) {
        atomicAdd(&hist[e0l[tid]], 1);
        atomicAdd(&hist[e1l[tid]], 1);
    }
    __syncthreads();
    // reserve global ranges: 8 global atomics per block
    if (tid < ENUM) cursor[tid] = atomicAdd(&counts[tid], hist[tid]);
    __syncthreads();
    // scatter token slots into reserved ranges
    if (tid < 64) {
        const int t = base + tid;
        int p0 = atomicAdd(&cursor[e0l[tid]], 1);
        toks[e0l[tid] * TOK + p0] = (t << 1);
        int p1 = atomicAdd(&cursor[e1l[tid]], 1);
        toks[e1l[tid] * TOK + p1] = (t << 1) | 1;
    }
}

// ---- up: Hbuf[slot] = silu(x@w1g[e]) * (x@w1u[e]); TM=128 TN=64, dbuf,
//      4 waves in 2x2, wave tile 64m x 32n; XOR-swizzled LDS (round-5) -----
__global__ __launch_bounds__(256, 4) void up_mfma(
    const ushort* __restrict__ xb, const ushort* __restrict__ BgP,
    const ushort* __restrict__ BuP, const int* __restrict__ counts,
    const int* __restrict__ toks, ushort* __restrict__ Hbuf)
{
    const int e = blockIdx.z;
    const int cnt = counts[e];
    const int m0 = blockIdx.y * 128;
    if (m0 >= cnt) return;
    const int nb = blockIdx.x;
    const int tid = threadIdx.x;
    const int w = tid >> 6;
    const int lane = tid & 63;
    const int q = lane >> 4;
    const int l15 = lane & 15;
    const int wr = w >> 1;   // 0..1 : m half (64 rows)
    const int wc = w & 1;    // 0..1 : n half (32 cols)

    __shared__ ushort As[2][128][32];
    __shared__ ushort Bgs[2][64][32];
    __shared__ ushort Bus[2][64][32];
    __shared__ int rowslot[128];

    if (tid < 128) rowslot[tid] = (m0 + tid < cnt) ? toks[e * TOK + m0 + tid] : -1;
    __syncthreads();

    const int srow = w * 16 + (lane >> 2);
    const int clog = (((lane & 3) + 4 - ((srow >> 1) & 3)) & 3) * 8;
    const int as0 = rowslot[srow];
    const int as1 = rowslot[srow + 64];
    const ushort* agp0 = xb + (size_t)(as0 < 0 ? 0 : (as0 >> 1)) * DDIM + clog;
    const ushort* agp1 = xb + (size_t)(as1 < 0 ? 0 : (as1 >> 1)) * DDIM + clog;
    const size_t tb = (size_t)(e * UP_NB + nb) * UP_KS * 2048;
    const ushort* bgp = BgP + tb + srow * 32 + clog;
    const ushort* bup = BuP + tb + srow * 32 + clog;

    const int coff = ((q + (l15 >> 1)) & 3) * 8;

    f32x4 accg[4][2], accu[4][2];
#pragma unroll
    for (int i = 0; i < 4; ++i)
#pragma unroll
        for (int j = 0; j < 2; ++j) { accg[i][j] = (f32x4)0.f; accu[i][j] = (f32x4)0.f; }

#define UP_PREFETCH(KSV, B)                                        \
    {                                                              \
        gl2lds16(agp0 + (KSV) * 32, &As[B][w * 16][0]);            \
        gl2lds16(agp1 + (KSV) * 32, &As[B][64 + w * 16][0]);       \
        gl2lds16(bgp + (size_t)(KSV) * 2048, &Bgs[B][w * 16][0]);  \
        gl2lds16(bup + (size_t)(KSV) * 2048, &Bus[B][w * 16][0]);  \
    }

    UP_PREFETCH(0, 0);
    __syncthreads();

    for (int ks = 0; ks < UP_KS; ++ks) {
        const int cur = ks & 1;
        const int nxt = cur ^ 1;
        if (ks + 1 < UP_KS) UP_PREFETCH(ks + 1, nxt);

        bf16x8 a[4], bg[2], bu[2];
#pragma unroll
        for (int mi = 0; mi < 4; ++mi)
            a[mi] = *(const bf16x8*)&As[cur][wr * 64 + mi * 16 + l15][coff];
#pragma unroll
        for (int ni = 0; ni < 2; ++ni) {
            bg[ni] = *(const bf16x8*)&Bgs[cur][wc * 32 + ni * 16 + l15][coff];
            bu[ni] = *(const bf16x8*)&Bus[cur][wc * 32 + ni * 16 + l15][coff];
        }
#pragma unroll
        for (int mi = 0; mi < 4; ++mi)
#pragma unroll
            for (int ni = 0; ni < 2; ++ni) {
                accg[mi][ni] = __builtin_amdgcn_mfma_f32_16x16x32_bf16(a[mi], bg[ni], accg[mi][ni], 0, 0, 0);
                accu[mi][ni] = __builtin_amdgcn_mfma_f32_16x16x32_bf16(a[mi], bu[ni], accu[mi][ni], 0, 0, 0);
            }
        __syncthreads();   // drains prefetch vmem + protects buffer swap
    }
#undef UP_PREFETCH

#pragma unroll
    for (int mi = 0; mi < 4; ++mi) {
#pragma unroll
        for (int r = 0; r < 4; ++r) {
            int ml = wr * 64 + mi * 16 + q * 4 + r;
            int slot = rowslot[ml];
            if (slot < 0) continue;
            ushort* hrow = Hbuf + (size_t)slot * HDIM + nb * 64 + wc * 32 + l15;
#pragma unroll
            for (int ni = 0; ni < 2; ++ni)
                hrow[ni * 16] = cvt_bf16(silu_f(accg[mi][ni][r]) * accu[mi][ni][r]);
        }
    }
}

// ---- down + combine: y[t] += wslot[slot] * (Hbuf[slot] @ w2[e]);
//      TM=128 TN=128, K-split 2, atomic fp32 epilogue (y pre-zeroed) -------
__global__ __launch_bounds__(256, 4) void down_mfma(
    const ushort* __restrict__ Hbuf, const ushort* __restrict__ W2P,
    const int* __restrict__ counts, const int* __restrict__ toks,
    const float* __restrict__ wslot, float* __restrict__ y)
{
    const int z = blockIdx.z;           // 0..15: expert*2 + K-half
    const int e = z >> 1;
    const int kh = z & 1;
    const int cnt = counts[e];
    const int m0 = blockIdx.y * 128;
    if (m0 >= cnt) return;
    const int nb = blockIdx.x;          // 0..7, 128-wide N blocks
    const int tid = threadIdx.x;
    const int w = tid >> 6;
    const int lane = tid & 63;
    const int q = lane >> 4;
    const int l15 = lane & 15;
    const int wr = w >> 1;
    const int wc = w & 1;

    __shared__ ushort As[2][128][32];
    __shared__ ushort Bs[2][128][32];
    __shared__ int rowslot[128];
    __shared__ float rowwt[128];

    if (tid < 128) {
        int s = (m0 + tid < cnt) ? toks[e * TOK + m0 + tid] : -1;
        rowslot[tid] = s;
        rowwt[tid] = (s < 0) ? 0.f : wslot[s];
    }
    __syncthreads();

    const int srow = w * 16 + (lane >> 2);
    const int clog = (((lane & 3) + 4 - ((srow >> 1) & 3)) & 3) * 8;
    const int as0 = rowslot[srow];
    const int as1 = rowslot[srow + 64];
    const ushort* agp0 = Hbuf + (size_t)(as0 < 0 ? 0 : as0) * HDIM + kh * (DN_KH * 32) + clog;
    const ushort* agp1 = Hbuf + (size_t)(as1 < 0 ? 0 : as1) * HDIM + kh * (DN_KH * 32) + clog;
    const int nb2 = nb * 2;
    const ushort* bp0 = W2P + ((size_t)(e * DN_NB + nb2) * DN_KS + kh * DN_KH) * 2048 + srow * 32 + clog;
    const ushort* bp1 = W2P + ((size_t)(e * DN_NB + nb2 + 1) * DN_KS + kh * DN_KH) * 2048 + srow * 32 + clog;

    const int coff = ((q + (l15 >> 1)) & 3) * 8;

    f32x4 acc[4][4];
#pragma unroll
    for (int i = 0; i < 4; ++i)
#pragma unroll
        for (int j = 0; j < 4; ++j) acc[i][j] = (f32x4)0.f;

#define DN_PREFETCH(KSV, B)                                           \
    {                                                                 \
        gl2lds16(agp0 + (KSV) * 32, &As[B][w * 16][0]);               \
        gl2lds16(agp1 + (KSV) * 32, &As[B][64 + w * 16][0]);          \
        gl2lds16(bp0 + (size_t)(KSV) * 2048, &Bs[B][w * 16][0]);      \
        gl2lds16(bp1 + (size_t)(KSV) * 2048, &Bs[B][64 + w * 16][0]); \
    }

    DN_PREFETCH(0, 0);
    __syncthreads();

    for (int ks = 0; ks < DN_KH; ++ks) {
        const int cur = ks & 1;
        const int nxt = cur ^ 1;
        if (ks + 1 < DN_KH) DN_PREFETCH(ks + 1, nxt);

        bf16x8 a[4], b[4];
#pragma unroll
        for (int mi = 0; mi < 4; ++mi)
            a[mi] = *(const bf16x8*)&As[cur][wr * 64 + mi * 16 + l15][coff];
#pragma unroll
        for (int ni = 0; ni < 4; ++ni)
            b[ni] = *(const bf16x8*)&Bs[cur][wc * 64 + ni * 16 + l15][coff];
#pragma unroll
        for (int mi = 0; mi < 4; ++mi)
#pragma unroll
            for (int ni = 0; ni < 4; ++ni)
                acc[mi][ni] = __builtin_amdgcn_mfma_f32_16x16x32_bf16(a[mi], b[ni], acc[mi][ni], 0, 0, 0);
        __syncthreads();
    }
#undef DN_PREFETCH

#pragma unroll
    for (int mi = 0; mi < 4; ++mi) {
#pragma unroll
        for (int r = 0; r < 4; ++r) {
            int ml = wr * 64 + mi * 16 + q * 4 + r;
            int slot = rowslot[ml];
            if (slot < 0) continue;
            float wv = rowwt[ml];
            float* yr = y + (size_t)(slot >> 1) * DDIM + nb * 128 + wc * 64 + l15;
#pragma unroll
            for (int ni = 0; ni < 4; ++ni)
                atomicAdd(&yr[ni * 16], wv * acc[mi][ni][r]);
        }
    }
}

extern "C" void kernel_launch(void* const* d_in, const int* in_sizes, int n_in,
                              void* d_out, int out_size, void* d_ws, size_t ws_size,
                              hipStream_t stream) {
    const float* x   = (const float*)d_in[0];
    const float* gw  = (const float*)d_in[1];
    const float* w1g = (const float*)d_in[2];
    const float* w1u = (const float*)d_in[3];
    const float* w2  = (const float*)d_in[4];
    float* y = (float*)d_out;
    char* ws = (char*)d_ws;

    // workspace layout (no Ybuf, no tinfo)
    size_t off = 0;
    int*    counts = (int*)(ws + off);   off += 256;
    int*    toks   = (int*)(ws + off);   off += (size_t)ENUM * TOK * 4;   // 64 KB
    float*  wslot  = (float*)(ws + off); off += (size_t)NSLOT * 4;        // 16 KB
    off = (off + 255) & ~(size_t)255;
    ushort* xb     = (ushort*)(ws + off); off += (size_t)TOK * DDIM * 2;  // 4 MB
    ushort* BgP  = (ushort*)(ws + off);  off += (size_t)ENUM * DDIM * HDIM * 2; // 23 MB
    ushort* BuP  = (ushort*)(ws + off);  off += (size_t)ENUM * DDIM * HDIM * 2; // 23 MB
    ushort* W2P  = (ushort*)(ws + off);  off += (size_t)ENUM * HDIM * DDIM * 2; // 23 MB
    ushort* Hbuf = (ushort*)(ws + off);                                         // 11.5 MB

    hipMemsetAsync(counts, 0, ENUM * sizeof(int), stream);
    hipMemsetAsync(y, 0, (size_t)TOK * DDIM * sizeof(float), stream);

    tcast_gate_kernel<<<CAST_ITEMS + GATE_BLKS, 256, 0, stream>>>(
        w1g, w1u, w2, BgP, BuP, W2P, x, gw, counts, toks, wslot, xb);

    up_mfma<<<dim3(UP_NB, TOK / 128, ENUM), 256, 0, stream>>>(xb, BgP, BuP, counts, toks, Hbuf);
    down_mfma<<<dim3(DDIM / 128, TOK / 128, 16), 256, 0, stream>>>(Hbuf, W2P, counts, toks, wslot, y);
}

// Round 9
// 263.109 us; speedup vs baseline: 2.8113x; 1.1765x over previous
//
#include <hip/hip_runtime.h>

#define TOK 2048
#define DDIM 1024
#define HDIM 1408
#define ENUM 8
#define NSLOT (2 * TOK)
#define UP_NB 22   // HDIM / 64
#define UP_KS 32   // DDIM / 32
#define DN_NB 16   // DDIM / 64
#define DN_KS 44   // HDIM / 32
#define DN_KH 22   // DN_KS / 2 (K-split halves)
#define W1C_BLK 512      // 16 z(e,tensor) * 32 ks — full-width 32-row slabs
#define CAST_BLKS 864    // + 8 e * 44 ks (w2)
#define GATE_BLK 512     // 2048 tokens / 4 per block

typedef unsigned int uint;
typedef unsigned short ushort;
typedef unsigned long long ull;

using bf16x8 = __attribute__((ext_vector_type(8))) __bf16;
using f32x4  = __attribute__((ext_vector_type(4))) float;

__device__ __forceinline__ float silu_f(float g) {
    return g / (1.0f + __expf(-g));
}

__device__ __forceinline__ ushort cvt_bf16(float f) {
    uint u = __float_as_uint(f);
    u += 0x7FFFu + ((u >> 16) & 1u);   // RNE
    return (ushort)(u >> 16);
}

// async global->LDS: per-lane global address, LDS dest = wave-uniform base + lane*16
__device__ __forceinline__ void gl2lds16(const void* g, void* l) {
    __builtin_amdgcn_global_load_lds(
        (const __attribute__((address_space(1))) uint*)g,
        (__attribute__((address_space(3))) uint*)l, 16, 0, 0);
}

// ---- cast slab body: one block = 32 rows x FULL width. Streams each row
//      sequentially (512B chunks), LDS [32][132] transpose, contiguous
//      32B/thread stores. New B layout: [e][ks][n(N)][kk(32)]. -------------
__device__ __forceinline__ void cast_slab(
    const float* __restrict__ src, ushort* __restrict__ dst,
    int N, int KS, int e, int ks, int tid, float (*Ls)[132])
{
    const float* sb = src + (size_t)e * ((size_t)KS * 32) * N + (size_t)(ks * 32) * N;
    ushort* db = dst + (size_t)(e * KS + ks) * N * 32;
    const int r = tid >> 3;            // 32 rows
    const int c16 = (tid & 7) * 16;    // 16 consecutive floats per thread
    const int nnl = tid >> 1;          // 128 cols per chunk
    const int kkh = (tid & 1) * 16;    // kk half

    for (int c0 = 0; c0 < N; c0 += 128) {
        const float* srow = sb + (size_t)r * N + c0 + c16;
        float4 v0 = *(const float4*)(srow + 0);
        float4 v1 = *(const float4*)(srow + 4);
        float4 v2 = *(const float4*)(srow + 8);
        float4 v3 = *(const float4*)(srow + 12);
        *(float4*)&Ls[r][c16 + 0]  = v0;
        *(float4*)&Ls[r][c16 + 4]  = v1;
        *(float4*)&Ls[r][c16 + 8]  = v2;
        *(float4*)&Ls[r][c16 + 12] = v3;
        __syncthreads();
        ushort o[16];
#pragma unroll
        for (int j = 0; j < 16; ++j) o[j] = cvt_bf16(Ls[kkh + j][nnl]);
        ushort* dt = db + (size_t)(c0 + nnl) * 32 + kkh;
        *(uint4*)(dt + 0) = *(uint4*)(o + 0);
        *(uint4*)(dt + 8) = *(uint4*)(o + 8);
        __syncthreads();
    }
}

// ---- kernel 1: weight precast (full-row streaming) + gate1 (round-5) -----
__global__ __launch_bounds__(256) void tcast_gate_kernel(
    const float* __restrict__ w1g, const float* __restrict__ w1u,
    const float* __restrict__ w2, ushort* __restrict__ BgP,
    ushort* __restrict__ BuP, ushort* __restrict__ W2P,
    const float* __restrict__ x, const float* __restrict__ gw,
    int* __restrict__ tinfo, float* __restrict__ wslot, ushort* __restrict__ xb)
{
    __shared__ float Ls[32][132];
    const int bid = blockIdx.x;
    const int tid = threadIdx.x;

    if (bid < W1C_BLK) {
        const int z = bid >> 5;             // 0..15: low 3 bits e, bit 3 tensor
        const int ks = bid & 31;
        cast_slab((z & 8) ? w1u : w1g, (z & 8) ? BuP : BgP,
                  HDIM, UP_KS, z & 7, ks, tid, Ls);
        return;
    }
    if (bid < CAST_BLKS) {
        const int b2 = bid - W1C_BLK;
        const int e = b2 / DN_KS;
        const int ks = b2 - e * DN_KS;
        cast_slab(w2, W2P, DDIM, DN_KS, e, ks, tid, Ls);
        return;
    }

    // ---- gate1: 4 tokens per block, one wave each (round-5 exact) ----
    const int t = (bid - CAST_BLKS) * 4 + (tid >> 6);
    const int lane = tid & 63;
    const float* xr = x + (size_t)t * DDIM;
    ushort* xbr = xb + (size_t)t * DDIM;
    float xv[16];
#pragma unroll
    for (int i = 0; i < 16; ++i) xv[i] = xr[lane + 64 * i];
#pragma unroll
    for (int i = 0; i < 16; ++i) xbr[lane + 64 * i] = cvt_bf16(xv[i]);
    float logit[ENUM];
#pragma unroll
    for (int e = 0; e < ENUM; ++e) {
        const float* gr = gw + (size_t)e * DDIM;
        float acc = 0.f;
#pragma unroll
        for (int i = 0; i < 16; ++i) acc += xv[i] * gr[lane + 64 * i];
#pragma unroll
        for (int s = 32; s > 0; s >>= 1) acc += __shfl_xor(acc, s, 64);
        logit[e] = acc;
    }
    if (lane == 0) {
        float mx = logit[0];
#pragma unroll
        for (int e = 1; e < ENUM; ++e) mx = fmaxf(mx, logit[e]);
        float p[ENUM]; float se = 0.f;
#pragma unroll
        for (int e = 0; e < ENUM; ++e) { p[e] = __expf(logit[e] - mx); se += p[e]; }
        float inv = 1.0f / se;
#pragma unroll
        for (int e = 0; e < ENUM; ++e) p[e] *= inv;
        int i0 = 0;
#pragma unroll
        for (int e = 1; e < ENUM; ++e) if (p[e] > p[i0]) i0 = e;
        int i1 = (i0 == 0) ? 1 : 0;
#pragma unroll
        for (int e = 0; e < ENUM; ++e) if (e != i0 && p[e] > p[i1]) i1 = e;
        tinfo[t] = i0 | (i1 << 4);
        wslot[(t << 1)] = p[i0];
        wslot[(t << 1) | 1] = p[i1];
    }
}

// ---- gate2: 8 blocks, wave-aggregated ballot compaction (round-5) --------
__global__ __launch_bounds__(256) void gate2_kernel(
    const int* __restrict__ tinfo, int* __restrict__ counts, int* __restrict__ toks)
{
    const int e = blockIdx.x;
    const int tid = threadIdx.x;
    const int lane = tid & 63;
    __shared__ int cnt;
    if (tid == 0) cnt = 0;
    __syncthreads();
    int* te = toks + e * TOK;
    for (int t = tid; t < TOK; t += 256) {
        int info = tinfo[t];
        ull m0 = __ballot((info & 15) == e);
        if (m0) {
            int base;
            if (lane == 0) base = atomicAdd(&cnt, __popcll(m0));
            base = __shfl(base, 0, 64);
            if ((m0 >> lane) & 1)
                te[base + __popcll(m0 & ((1ull << lane) - 1))] = (t << 1);
        }
        ull m1 = __ballot((info >> 4) == e);
        if (m1) {
            int base;
            if (lane == 0) base = atomicAdd(&cnt, __popcll(m1));
            base = __shfl(base, 0, 64);
            if ((m1 >> lane) & 1)
                te[base + __popcll(m1 & ((1ull << lane) - 1))] = (t << 1) | 1;
        }
    }
    __syncthreads();
    if (tid == 0) counts[e] = cnt;
}

// ---- up: Hbuf[slot] = silu(x@w1g[e]) * (x@w1u[e]); TM=128 TN=64, dbuf,
//      4 waves in 2x2, wave tile 64m x 32n; XOR-swizzled LDS (round-5;
//      only B base addressing changed for the new slab layout) -------------
__global__ __launch_bounds__(256, 4) void up_mfma(
    const ushort* __restrict__ xb, const ushort* __restrict__ BgP,
    const ushort* __restrict__ BuP, const int* __restrict__ counts,
    const int* __restrict__ toks, ushort* __restrict__ Hbuf)
{
    const int e = blockIdx.z;
    const int cnt = counts[e];
    const int m0 = blockIdx.y * 128;
    if (m0 >= cnt) return;
    const int nb = blockIdx.x;
    const int tid = threadIdx.x;
    const int w = tid >> 6;
    const int lane = tid & 63;
    const int q = lane >> 4;
    const int l15 = lane & 15;
    const int wr = w >> 1;   // 0..1 : m half (64 rows)
    const int wc = w & 1;    // 0..1 : n half (32 cols)

    __shared__ ushort As[2][128][32];
    __shared__ ushort Bgs[2][64][32];
    __shared__ ushort Bus[2][64][32];
    __shared__ int rowslot[128];

    if (tid < 128) rowslot[tid] = (m0 + tid < cnt) ? toks[e * TOK + m0 + tid] : -1;
    __syncthreads();

    const int srow = w * 16 + (lane >> 2);
    const int clog = (((lane & 3) + 4 - ((srow >> 1) & 3)) & 3) * 8;
    const int as0 = rowslot[srow];
    const int as1 = rowslot[srow + 64];
    const ushort* agp0 = xb + (size_t)(as0 < 0 ? 0 : (as0 >> 1)) * DDIM + clog;
    const ushort* agp1 = xb + (size_t)(as1 < 0 ? 0 : (as1 >> 1)) * DDIM + clog;
    // new layout: [e][ks][n(HDIM)][kk32]; tile (e,ks,nb) = contiguous 4KB
    const size_t tb = (size_t)e * (UP_KS * HDIM * 32) + (size_t)nb * 2048;
    const ushort* bgp = BgP + tb + srow * 32 + clog;
    const ushort* bup = BuP + tb + srow * 32 + clog;

    const int coff = ((q + (l15 >> 1)) & 3) * 8;

    f32x4 accg[4][2], accu[4][2];
#pragma unroll
    for (int i = 0; i < 4; ++i)
#pragma unroll
        for (int j = 0; j < 2; ++j) { accg[i][j] = (f32x4)0.f; accu[i][j] = (f32x4)0.f; }

#define UP_PREFETCH(KSV, B)                                                    \
    {                                                                          \
        gl2lds16(agp0 + (KSV) * 32, &As[B][w * 16][0]);                        \
        gl2lds16(agp1 + (KSV) * 32, &As[B][64 + w * 16][0]);                   \
        gl2lds16(bgp + (size_t)(KSV) * (HDIM * 32), &Bgs[B][w * 16][0]);       \
        gl2lds16(bup + (size_t)(KSV) * (HDIM * 32), &Bus[B][w * 16][0]);       \
    }

    UP_PREFETCH(0, 0);
    __syncthreads();

    for (int ks = 0; ks < UP_KS; ++ks) {
        const int cur = ks & 1;
        const int nxt = cur ^ 1;
        if (ks + 1 < UP_KS) UP_PREFETCH(ks + 1, nxt);

        bf16x8 a[4], bg[2], bu[2];
#pragma unroll
        for (int mi = 0; mi < 4; ++mi)
            a[mi] = *(const bf16x8*)&As[cur][wr * 64 + mi * 16 + l15][coff];
#pragma unroll
        for (int ni = 0; ni < 2; ++ni) {
            bg[ni] = *(const bf16x8*)&Bgs[cur][wc * 32 + ni * 16 + l15][coff];
            bu[ni] = *(const bf16x8*)&Bus[cur][wc * 32 + ni * 16 + l15][coff];
        }
#pragma unroll
        for (int mi = 0; mi < 4; ++mi)
#pragma unroll
            for (int ni = 0; ni < 2; ++ni) {
                accg[mi][ni] = __builtin_amdgcn_mfma_f32_16x16x32_bf16(a[mi], bg[ni], accg[mi][ni], 0, 0, 0);
                accu[mi][ni] = __builtin_amdgcn_mfma_f32_16x16x32_bf16(a[mi], bu[ni], accu[mi][ni], 0, 0, 0);
            }
        __syncthreads();   // drains prefetch vmem + protects buffer swap
    }
#undef UP_PREFETCH

#pragma unroll
    for (int mi = 0; mi < 4; ++mi) {
#pragma unroll
        for (int r = 0; r < 4; ++r) {
            int ml = wr * 64 + mi * 16 + q * 4 + r;
            int slot = rowslot[ml];
            if (slot < 0) continue;
            ushort* hrow = Hbuf + (size_t)slot * HDIM + nb * 64 + wc * 32 + l15;
#pragma unroll
            for (int ni = 0; ni < 2; ++ni)
                hrow[ni * 16] = cvt_bf16(silu_f(accg[mi][ni][r]) * accu[mi][ni][r]);
        }
    }
}

// ---- down: Ybuf partials = Hbuf[slot] @ w2[e]; TM=128 TN=128, K-split 2,
//      dbuf, swizzled (round-5; only B base addressing changed) ------------
__global__ __launch_bounds__(256, 4) void down_mfma(
    const ushort* __restrict__ Hbuf, const ushort* __restrict__ W2P,
    const int* __restrict__ counts, const int* __restrict__ toks,
    float* __restrict__ Ybuf)
{
    const int z = blockIdx.z;           // 0..15: expert*2 + K-half
    const int e = z >> 1;
    const int kh = z & 1;
    const int cnt = counts[e];
    const int m0 = blockIdx.y * 128;
    if (m0 >= cnt) return;
    const int nb = blockIdx.x;          // 0..7, 128-wide N blocks
    const int tid = threadIdx.x;
    const int w = tid >> 6;
    const int lane = tid & 63;
    const int q = lane >> 4;
    const int l15 = lane & 15;
    const int wr = w >> 1;
    const int wc = w & 1;

    __shared__ ushort As[2][128][32];
    __shared__ ushort Bs[2][128][32];
    __shared__ int rowslot[128];

    if (tid < 128) rowslot[tid] = (m0 + tid < cnt) ? toks[e * TOK + m0 + tid] : -1;
    __syncthreads();

    const int srow = w * 16 + (lane >> 2);
    const int clog = (((lane & 3) + 4 - ((srow >> 1) & 3)) & 3) * 8;
    const int as0 = rowslot[srow];
    const int as1 = rowslot[srow + 64];
    const ushort* agp0 = Hbuf + (size_t)(as0 < 0 ? 0 : as0) * HDIM + kh * (DN_KH * 32) + clog;
    const ushort* agp1 = Hbuf + (size_t)(as1 < 0 ? 0 : as1) * HDIM + kh * (DN_KH * 32) + clog;
    // new layout: [e][ks][n(DDIM)][kk32]; two adjacent 64-col tiles = +2048
    const size_t bb = ((size_t)e * DN_KS + kh * DN_KH) * (DDIM * 32) + (size_t)nb * 4096;
    const ushort* bp0 = W2P + bb + srow * 32 + clog;
    const ushort* bp1 = bp0 + 2048;

    const int coff = ((q + (l15 >> 1)) & 3) * 8;

    f32x4 acc[4][4];
#pragma unroll
    for (int i = 0; i < 4; ++i)
#pragma unroll
        for (int j = 0; j < 4; ++j) acc[i][j] = (f32x4)0.f;

#define DN_PREFETCH(KSV, B)                                                      \
    {                                                                            \
        gl2lds16(agp0 + (KSV) * 32, &As[B][w * 16][0]);                          \
        gl2lds16(agp1 + (KSV) * 32, &As[B][64 + w * 16][0]);                     \
        gl2lds16(bp0 + (size_t)(KSV) * (DDIM * 32), &Bs[B][w * 16][0]);          \
        gl2lds16(bp1 + (size_t)(KSV) * (DDIM * 32), &Bs[B][64 + w * 16][0]);     \
    }

    DN_PREFETCH(0, 0);
    __syncthreads();

    for (int ks = 0; ks < DN_KH; ++ks) {
        const int cur = ks & 1;
        const int nxt = cur ^ 1;
        if (ks + 1 < DN_KH) DN_PREFETCH(ks + 1, nxt);

        bf16x8 a[4], b[4];
#pragma unroll
        for (int mi = 0; mi < 4; ++mi)
            a[mi] = *(const bf16x8*)&As[cur][wr * 64 + mi * 16 + l15][coff];
#pragma unroll
        for (int ni = 0; ni < 4; ++ni)
            b[ni] = *(const bf16x8*)&Bs[cur][wc * 64 + ni * 16 + l15][coff];
#pragma unroll
        for (int mi = 0; mi < 4; ++mi)
#pragma unroll
            for (int ni = 0; ni < 4; ++ni)
                acc[mi][ni] = __builtin_amdgcn_mfma_f32_16x16x32_bf16(a[mi], b[ni], acc[mi][ni], 0, 0, 0);
        __syncthreads();
    }
#undef DN_PREFETCH

    float* Yp = Ybuf + (size_t)kh * NSLOT * DDIM;
#pragma unroll
    for (int mi = 0; mi < 4; ++mi) {
#pragma unroll
        for (int r = 0; r < 4; ++r) {
            int ml = wr * 64 + mi * 16 + q * 4 + r;
            int slot = rowslot[ml];
            if (slot < 0) continue;
            float* yr = Yp + (size_t)slot * DDIM + nb * 128 + wc * 64 + l15;
#pragma unroll
            for (int ni = 0; ni < 4; ++ni)
                yr[ni * 16] = acc[mi][ni][r];
        }
    }
}

// ---- combine: y[t] = w0*(Y0[2t]+Y1[2t]) + w1*(Y0[2t+1]+Y1[2t+1]) ---------
__global__ __launch_bounds__(256) void combine_kernel(
    const float* __restrict__ Ybuf, const float* __restrict__ wslot,
    float* __restrict__ y)
{
    const int t = blockIdx.x;
    const int j = threadIdx.x * 4;
    const float w0 = wslot[2 * t];
    const float w1 = wslot[2 * t + 1];
    const float* y00 = Ybuf + ((size_t)2 * t) * DDIM + j;
    const float* y01 = Ybuf + ((size_t)2 * t + 1) * DDIM + j;
    const float* y10 = y00 + (size_t)NSLOT * DDIM;
    const float* y11 = y01 + (size_t)NSLOT * DDIM;
    float4 a0 = *(const float4*)y00;
    float4 b0 = *(const float4*)y01;
    float4 a1 = *(const float4*)y10;
    float4 b1 = *(const float4*)y11;
    float4 o;
    o.x = w0 * (a0.x + a1.x) + w1 * (b0.x + b1.x);
    o.y = w0 * (a0.y + a1.y) + w1 * (b0.y + b1.y);
    o.z = w0 * (a0.z + a1.z) + w1 * (b0.z + b1.z);
    o.w = w0 * (a0.w + a1.w) + w1 * (b0.w + b1.w);
    *(float4*)(y + (size_t)t * DDIM + j) = o;
}

extern "C" void kernel_launch(void* const* d_in, const int* in_sizes, int n_in,
                              void* d_out, int out_size, void* d_ws, size_t ws_size,
                              hipStream_t stream) {
    const float* x   = (const float*)d_in[0];
    const float* gw  = (const float*)d_in[1];
    const float* w1g = (const float*)d_in[2];
    const float* w1u = (const float*)d_in[3];
    const float* w2  = (const float*)d_in[4];
    float* y = (float*)d_out;
    char* ws = (char*)d_ws;

    // workspace layout (Ybuf [2 K-halves] aliases BgP/BuP region — dead after up)
    size_t off = 0;
    int*    counts = (int*)(ws + off);   off += 256;
    int*    toks   = (int*)(ws + off);   off += (size_t)ENUM * TOK * 4;   // 64 KB
    float*  wslot  = (float*)(ws + off); off += (size_t)NSLOT * 4;        // 16 KB
    int*    tinfo  = (int*)(ws + off);   off += (size_t)TOK * 4;          // 8 KB
    off = (off + 255) & ~(size_t)255;
    ushort* xb     = (ushort*)(ws + off); off += (size_t)TOK * DDIM * 2;  // 4 MB
    size_t regA = off;                                                    // 46 MB region
    ushort* BgP  = (ushort*)(ws + regA);
    ushort* BuP  = (ushort*)(ws + regA + (size_t)ENUM * DDIM * HDIM * 2);
    float*  Ybuf = (float*)(ws + regA);                                   // 33.6 MB alias
    off = regA + (size_t)2 * ENUM * DDIM * HDIM * 2;
    ushort* W2P  = (ushort*)(ws + off);  off += (size_t)ENUM * HDIM * DDIM * 2; // 23 MB
    ushort* Hbuf = (ushort*)(ws + off);                                         // 11.5 MB

    tcast_gate_kernel<<<CAST_BLKS + GATE_BLK, 256, 0, stream>>>(
        w1g, w1u, w2, BgP, BuP, W2P, x, gw, tinfo, wslot, xb);
    gate2_kernel<<<ENUM, 256, 0, stream>>>(tinfo, counts, toks);

    up_mfma<<<dim3(UP_NB, TOK / 128, ENUM), 256, 0, stream>>>(xb, BgP, BuP, counts, toks, Hbuf);
    down_mfma<<<dim3(DDIM / 128, TOK / 128, 16), 256, 0, stream>>>(Hbuf, W2P, counts, toks, Ybuf);
    combine_kernel<<<TOK, 256, 0, stream>>>(Ybuf, wslot, y);
}